// Round 4
// baseline (2640.619 us; speedup 1.0000x reference)
//
#include <hip/hip_runtime.h>

// ASIF multi-head attention + HIE, MI355X (gfx950). ALL I/O fp32.
// B=256, S=200, D=256, H=4, HD=64, R=16.
// Round 3: single fused attention kernel (3 branches, shared scores),
// quarter-batch chunking for arena pressure. HIE chain fp32/double.

constexpr int B_ = 256, S_ = 200, D_ = 256, H_ = 4, R_ = 16;
constexpr int M_ = B_ * S_;                    // 51200
constexpr size_t BSD = (size_t)B_ * S_ * D_;   // 13,107,200
constexpr size_t QUART = BSD / 4;              // 3,276,800 (64 batches)
constexpr int MQ = 64 * 200;                   // 12800 rows per quarter

// ---------------------------------------------------------------------------
// GEMM: Y(f32, M x 256) = X(f32 M x 256) @ W(f32 256x256) + bias
// 128x128 tile, BK=32, 8x8 per thread.
// ---------------------------------------------------------------------------
__global__ __launch_bounds__(256) void gemm_proj(
    const float* __restrict__ X, const float* __restrict__ W,
    const float* __restrict__ bias, float* __restrict__ Y)
{
  __shared__ float Xs[32][132];   // [k][m]
  __shared__ float Ws[32][132];   // [k][n]
  const int t = threadIdx.x;
  const int tm = t >> 4, tn = t & 15;
  const int m0 = blockIdx.x * 128, n0 = blockIdx.y * 128;
  float acc[8][8];
#pragma unroll
  for (int i = 0; i < 8; ++i)
#pragma unroll
    for (int j = 0; j < 8; ++j) acc[i][j] = 0.f;

  for (int k0 = 0; k0 < 256; k0 += 32) {
#pragma unroll
    for (int i = 0; i < 4; ++i) {
      int idx = t + i * 256;            // 0..1023
      int r = idx >> 3, c4 = (idx & 7) << 2;
      float4 v = *reinterpret_cast<const float4*>(X + (size_t)(m0 + r) * 256 + k0 + c4);
      Xs[c4 + 0][r] = v.x; Xs[c4 + 1][r] = v.y; Xs[c4 + 2][r] = v.z; Xs[c4 + 3][r] = v.w;
    }
#pragma unroll
    for (int i = 0; i < 4; ++i) {
      int idx = t + i * 256;            // 0..1023
      int r = idx >> 5, c4 = (idx & 31) << 2;
      float4 v = *reinterpret_cast<const float4*>(W + (size_t)(k0 + r) * 256 + n0 + c4);
      Ws[r][c4 + 0] = v.x; Ws[r][c4 + 1] = v.y; Ws[r][c4 + 2] = v.z; Ws[r][c4 + 3] = v.w;
    }
    __syncthreads();
#pragma unroll
    for (int kk = 0; kk < 32; ++kk) {
      float a[8], b[8];
      *reinterpret_cast<float4*>(&a[0]) = *reinterpret_cast<const float4*>(&Xs[kk][tm * 4]);
      *reinterpret_cast<float4*>(&a[4]) = *reinterpret_cast<const float4*>(&Xs[kk][tm * 4 + 64]);
      *reinterpret_cast<float4*>(&b[0]) = *reinterpret_cast<const float4*>(&Ws[kk][tn * 4]);
      *reinterpret_cast<float4*>(&b[4]) = *reinterpret_cast<const float4*>(&Ws[kk][tn * 4 + 64]);
#pragma unroll
      for (int i = 0; i < 8; ++i)
#pragma unroll
        for (int j = 0; j < 8; ++j) acc[i][j] = fmaf(a[i], b[j], acc[i][j]);
    }
    __syncthreads();
  }
#pragma unroll
  for (int i = 0; i < 8; ++i) {
    int m = m0 + ((i < 4) ? (tm * 4 + i) : (64 + tm * 4 + i - 4));
#pragma unroll
    for (int jj = 0; jj < 2; ++jj) {
      int n = n0 + (jj == 0 ? tn * 4 : 64 + tn * 4);
      float4 bb = *reinterpret_cast<const float4*>(bias + n);
      float4 ov;
      ov.x = acc[i][jj * 4 + 0] + bb.x;
      ov.y = acc[i][jj * 4 + 1] + bb.y;
      ov.z = acc[i][jj * 4 + 2] + bb.z;
      ov.w = acc[i][jj * 4 + 3] + bb.w;
      *reinterpret_cast<float4*>(Y + (size_t)m * 256 + n) = ov;
    }
  }
}

// ---------------------------------------------------------------------------
// Fused 3-branch attention. Thread = (q_local 0..63, d_group 0..3).
// Per thread: persistent qf/qp fragments (16 each), ctx 3x16, online softmax
// state x3. Score dots partial over 16 d, reduced across the 4 d-group lanes
// (adjacent lanes) via shfl_xor(1),(2). Probs identical across the 4 lanes.
// Grid: (qtile=4, h=4, b=64). No buffer aliasing (ctx outputs are separate).
// ---------------------------------------------------------------------------
__global__ __launch_bounds__(256) void fused_attn(
    const float* __restrict__ Qf, const float* __restrict__ Kf,
    const float* __restrict__ Qp, const float* __restrict__ Kp,
    const float* __restrict__ Vi, const float* __restrict__ Vf,
    const float* __restrict__ Vp, const float* __restrict__ mask,
    float* __restrict__ Ch, float* __restrict__ Cf, float* __restrict__ Cp)
{
  __shared__ float kft[16][64], kpt[16][64];
  __shared__ float vit[16][64], vft[16][64], vpt[16][64];
  __shared__ float mt[16];
  const int t = threadIdx.x;
  const int ql = t >> 2, dg = t & 3;
  const int q0 = blockIdx.x * 64;
  const int h  = blockIdx.y;
  const int b  = blockIdx.z;
  const int q  = q0 + ql;
  const bool act = (q < 200);
  const int d0 = dg * 16;
  const size_t rowbase = ((size_t)b * 200 + (act ? q : 0)) * 256 + (size_t)h * 64 + d0;
  float qf[16], qp[16];
#pragma unroll
  for (int u = 0; u < 16; u += 4) {
    *reinterpret_cast<float4*>(&qf[u]) = *reinterpret_cast<const float4*>(Qf + rowbase + u);
    *reinterpret_cast<float4*>(&qp[u]) = *reinterpret_cast<const float4*>(Qp + rowbase + u);
  }
  float cH[16], cF[16], cP[16];
#pragma unroll
  for (int d = 0; d < 16; ++d) { cH[d] = 0.f; cF[d] = 0.f; cP[d] = 0.f; }
  float mh = -1e30f, lh = 0.f, mf = -1e30f, lf = 0.f, mp = -1e30f, lp = 0.f;

  for (int kt = 0; kt < 200; kt += 16) {
    const int kn = (200 - kt < 16) ? (200 - kt) : 16;
    {
      const int r = t >> 4, c4 = (t & 15) << 2;
      if (r < kn) {
        const size_t src = ((size_t)b * 200 + kt + r) * 256 + (size_t)h * 64 + c4;
        *reinterpret_cast<float4*>(&kft[r][c4]) = *reinterpret_cast<const float4*>(Kf + src);
        *reinterpret_cast<float4*>(&kpt[r][c4]) = *reinterpret_cast<const float4*>(Kp + src);
        *reinterpret_cast<float4*>(&vit[r][c4]) = *reinterpret_cast<const float4*>(Vi + src);
        *reinterpret_cast<float4*>(&vft[r][c4]) = *reinterpret_cast<const float4*>(Vf + src);
        *reinterpret_cast<float4*>(&vpt[r][c4]) = *reinterpret_cast<const float4*>(Vp + src);
      }
      if (t < 16) mt[t] = (kt + t < 200) ? mask[(size_t)b * 200 + kt + t] : -1e30f;
    }
    __syncthreads();
    if (act) {
      float ri[16], rp[16], sb[16];
      // partial dots over this lane's 16 d, reduced across 4 adjacent lanes
#pragma unroll
      for (int j = 0; j < 16; ++j) {
        float ai = 0.f, ap = 0.f;
#pragma unroll
        for (int d = 0; d < 16; ++d) {
          ai = fmaf(qf[d], kft[j][d0 + d], ai);
          ap = fmaf(qp[d], kpt[j][d0 + d], ap);
        }
        ai += __shfl_xor(ai, 1); ai += __shfl_xor(ai, 2);
        ap += __shfl_xor(ap, 1); ap += __shfl_xor(ap, 2);
        ri[j] = ai; rp[j] = ap;
      }
      float tmi = -1e30f, tmpv = -1e30f, tmb = -1e30f;
#pragma unroll
      for (int j = 0; j < 16; ++j) {
        float si = ri[j] * 0.125f + mt[j];      // item score (+mask)
        float sp = rp[j] * 0.125f + mt[j];      // pos score (+mask)
        float bb = si + rp[j] * 0.125f;         // both = (ri+rp)*0.125 + mask
        ri[j] = si; rp[j] = sp; sb[j] = bb;
        tmi = fmaxf(tmi, si); tmpv = fmaxf(tmpv, sp); tmb = fmaxf(tmb, bb);
      }
      const float mhn = fmaxf(mh, tmb), sch = __expf(mh - mhn);
      const float mfn = fmaxf(mf, tmi), scf = __expf(mf - mfn);
      const float mpn = fmaxf(mp, tmpv), scp = __expf(mp - mpn);
      mh = mhn; mf = mfn; mp = mpn;
      lh *= sch; lf *= scf; lp *= scp;
#pragma unroll
      for (int j = 0; j < 16; ++j) {
        float pb = __expf(sb[j] - mh); lh += pb; sb[j] = pb;
        float pi = __expf(ri[j] - mf); lf += pi; ri[j] = pi;
        float pp = __expf(rp[j] - mp); lp += pp; rp[j] = pp;
      }
#pragma unroll
      for (int d = 0; d < 16; ++d) { cH[d] *= sch; cF[d] *= scf; cP[d] *= scp; }
#pragma unroll
      for (int j = 0; j < 16; ++j) {
        const float pb = sb[j], pi = ri[j], pp = rp[j];
#pragma unroll
        for (int d = 0; d < 16; ++d) {
          cH[d] = fmaf(pb, vit[j][d0 + d], cH[d]);
          cF[d] = fmaf(pi, vft[j][d0 + d], cF[d]);
          cP[d] = fmaf(pp, vpt[j][d0 + d], cP[d]);
        }
      }
    }
    __syncthreads();
  }
  if (act) {
    const float ih = 1.f / lh, iff = 1.f / lf, ip = 1.f / lp;
#pragma unroll
    for (int u = 0; u < 16; u += 4) {
      float4 o;
      o.x = cH[u + 0] * ih; o.y = cH[u + 1] * ih; o.z = cH[u + 2] * ih; o.w = cH[u + 3] * ih;
      *reinterpret_cast<float4*>(Ch + rowbase + u) = o;
      o.x = cF[u + 0] * iff; o.y = cF[u + 1] * iff; o.z = cF[u + 2] * iff; o.w = cF[u + 3] * iff;
      *reinterpret_cast<float4*>(Cf + rowbase + u) = o;
      o.x = cP[u + 0] * ip; o.y = cP[u + 1] * ip; o.z = cP[u + 2] * ip; o.w = cP[u + 3] * ip;
      *reinterpret_cast<float4*>(Cp + rowbase + u) = o;
    }
  }
}

// ---------------------------------------------------------------------------
// Fused dense + residual + LayerNorm. BM=64, BN=256 (full row per block).
// In-place X==out safe (block-disjoint rows; all reads precede writes).
// ---------------------------------------------------------------------------
__global__ __launch_bounds__(256) void dense_ln_kernel(
    const float* __restrict__ X, const float* __restrict__ W,
    const float* __restrict__ bias, const float* __restrict__ resid,
    const float* __restrict__ gv, const float* __restrict__ bv,
    float* __restrict__ out)
{
  __shared__ float Xs[32][68];     // [k][m]
  __shared__ float Ws[32][260];    // [k][n]
  const int t = threadIdx.x;
  const int m0 = blockIdx.x * 64;
  const int tm = t >> 4, tn = t & 15;
  float acc[4][16];
#pragma unroll
  for (int r = 0; r < 4; ++r)
#pragma unroll
    for (int c = 0; c < 16; ++c) acc[r][c] = 0.f;

  for (int k0 = 0; k0 < 256; k0 += 32) {
#pragma unroll
    for (int i = 0; i < 2; ++i) {
      int idx = t + i * 256;
      int r = idx >> 3, c4 = (idx & 7) << 2;
      float4 v = *reinterpret_cast<const float4*>(X + (size_t)(m0 + r) * 256 + k0 + c4);
      Xs[c4 + 0][r] = v.x; Xs[c4 + 1][r] = v.y; Xs[c4 + 2][r] = v.z; Xs[c4 + 3][r] = v.w;
    }
#pragma unroll
    for (int i = 0; i < 8; ++i) {
      int idx = t + i * 256;
      int r = idx >> 6, c4 = (idx & 63) << 2;
      float4 v = *reinterpret_cast<const float4*>(W + (size_t)(k0 + r) * 256 + c4);
      Ws[r][c4 + 0] = v.x; Ws[r][c4 + 1] = v.y; Ws[r][c4 + 2] = v.z; Ws[r][c4 + 3] = v.w;
    }
    __syncthreads();
#pragma unroll
    for (int kk = 0; kk < 32; ++kk) {
      float a[4], b[16];
      *reinterpret_cast<float4*>(a) = *reinterpret_cast<const float4*>(&Xs[kk][tm * 4]);
#pragma unroll
      for (int ch = 0; ch < 4; ++ch)
        *reinterpret_cast<float4*>(&b[ch * 4]) =
            *reinterpret_cast<const float4*>(&Ws[kk][ch * 64 + tn * 4]);
#pragma unroll
      for (int r = 0; r < 4; ++r)
#pragma unroll
        for (int c = 0; c < 16; ++c) acc[r][c] = fmaf(a[r], b[c], acc[r][c]);
    }
    __syncthreads();
  }
#pragma unroll
  for (int r = 0; r < 4; ++r) {
    int m = m0 + tm * 4 + r;
#pragma unroll
    for (int ch = 0; ch < 4; ++ch) {
      int n = ch * 64 + tn * 4;
      float4 rr = *reinterpret_cast<const float4*>(resid + (size_t)m * 256 + n);
      float4 bb = *reinterpret_cast<const float4*>(bias + n);
      acc[r][ch * 4 + 0] += rr.x + bb.x;
      acc[r][ch * 4 + 1] += rr.y + bb.y;
      acc[r][ch * 4 + 2] += rr.z + bb.z;
      acc[r][ch * 4 + 3] += rr.w + bb.w;
    }
  }
#pragma unroll
  for (int r = 0; r < 4; ++r) {
    float s = 0.f;
#pragma unroll
    for (int c = 0; c < 16; ++c) s += acc[r][c];
    s += __shfl_xor(s, 1); s += __shfl_xor(s, 2);
    s += __shfl_xor(s, 4); s += __shfl_xor(s, 8);
    const float mean = s * (1.0f / 256.0f);
    float vs = 0.f;
#pragma unroll
    for (int c = 0; c < 16; ++c) { float d = acc[r][c] - mean; vs += d * d; }
    vs += __shfl_xor(vs, 1); vs += __shfl_xor(vs, 2);
    vs += __shfl_xor(vs, 4); vs += __shfl_xor(vs, 8);
    const float rstd = rsqrtf(vs * (1.0f / 256.0f) + 1e-12f);
    int m = m0 + tm * 4 + r;
#pragma unroll
    for (int ch = 0; ch < 4; ++ch) {
      int n = ch * 64 + tn * 4;
      float4 gg = *reinterpret_cast<const float4*>(gv + n);
      float4 be = *reinterpret_cast<const float4*>(bv + n);
      float4 ov;
      ov.x = (acc[r][ch * 4 + 0] - mean) * rstd * gg.x + be.x;
      ov.y = (acc[r][ch * 4 + 1] - mean) * rstd * gg.y + be.y;
      ov.z = (acc[r][ch * 4 + 2] - mean) * rstd * gg.z + be.z;
      ov.w = (acc[r][ch * 4 + 3] - mean) * rstd * gg.w + be.w;
      *reinterpret_cast<float4*>(out + (size_t)m * 256 + n) = ov;
    }
  }
}

// ---------------------------------------------------------------------------
// HIE kernels (unchanged, proven).
// ---------------------------------------------------------------------------
__global__ __launch_bounds__(256) void hie_hr_kernel(
    const float* __restrict__ h, const float* __restrict__ Wr, float* __restrict__ hr)
{
  __shared__ float wrs[3200];
  const int b = blockIdx.x, t = threadIdx.x;
  for (int i = t; i < 3200; i += 256) wrs[i] = Wr[i];
  __syncthreads();
  double acc[16];
#pragma unroll
  for (int r = 0; r < 16; ++r) acc[r] = 0.0;
  const float* hb = h + (size_t)b * 200 * 256;
  for (int n = 0; n < 200; ++n) {
    float hv = hb[(size_t)n * 256 + t];
#pragma unroll
    for (int r = 0; r < 16; ++r) acc[r] += (double)(hv * wrs[n * 16 + r]);
  }
#pragma unroll
  for (int r = 0; r < 16; ++r) hr[((size_t)b * 16 + r) * 256 + t] = (float)acc[r];
}

__global__ __launch_bounds__(256) void hie_qr_kernel(
    const float* __restrict__ hr, float* __restrict__ Qg)
{
  __shared__ float Qs[16][256];
  __shared__ double red[4];
  const int b = blockIdx.x, t = threadIdx.x;
  const int wid = t >> 6, lane = t & 63;
  const float* A = hr + (size_t)b * 4096;
#pragma unroll 1
  for (int j = 0; j < 16; ++j) {
    double v = (double)A[j * 256 + t];
#pragma unroll 1
    for (int i = 0; i < j; ++i) {
      float qi = Qs[i][t];
      double p = (double)qi * v;
#pragma unroll
      for (int off = 32; off; off >>= 1) p += __shfl_xor(p, off);
      if (lane == 0) red[wid] = p;
      __syncthreads();
      double dot = red[0] + red[1] + red[2] + red[3];
      __syncthreads();
      v -= dot * (double)qi;
    }
    double nn = v * v;
#pragma unroll
    for (int off = 32; off; off >>= 1) nn += __shfl_xor(nn, off);
    if (lane == 0) red[wid] = nn;
    __syncthreads();
    double nrm = sqrt(red[0] + red[1] + red[2] + red[3]);
    __syncthreads();
    float qv = (float)(v / nrm);
    Qs[j][t] = qv;
    Qg[(size_t)b * 4096 + j * 256 + t] = qv;
    __syncthreads();
  }
}

template<bool GATE>
__global__ __launch_bounds__(256) void hie_px_kernel(
    const float* __restrict__ X, const float* __restrict__ Qg,
    const float* __restrict__ pxin, float* __restrict__ outp)
{
  __shared__ float Qs[16][260];
  __shared__ float ht[16][260];
  const int b = blockIdx.x, t = threadIdx.x;
  for (int i = t; i < 4096; i += 256) Qs[i >> 8][i & 255] = Qg[(size_t)b * 4096 + i];
  const int nl = t >> 4, r = t & 15;
  for (int chunk = 0; chunk < 200; chunk += 16) {
    __syncthreads();
#pragma unroll
    for (int i = 0; i < 4; ++i) {
      int c = t + i * 256;
      int rr = c >> 6, c4 = (c & 63) << 2;
      int n = chunk + rr;
      if (n < 200)
        *reinterpret_cast<float4*>(&ht[rr][c4]) =
            *reinterpret_cast<const float4*>(X + ((size_t)b * 200 + n) * 256 + c4);
    }
    __syncthreads();
    int n = chunk + nl;
    if (n < 200) {
      double acc = 0.0;
#pragma unroll
      for (int d4 = 0; d4 < 256; d4 += 4) {
        float4 hv = *reinterpret_cast<const float4*>(&ht[nl][d4]);
        float4 qv = *reinterpret_cast<const float4*>(&Qs[r][d4]);
        acc += (double)(hv.x * qv.x + hv.y * qv.y + hv.z * qv.z + hv.w * qv.w);
      }
      float a = (float)acc;
      size_t oi = ((size_t)b * 200 + n) * 16 + r;
      if (GATE) {
        float px = pxin[oi];
        outp[oi] = (px * a > 0.0f) ? a : 0.0f;
      } else {
        outp[oi] = a;
      }
    }
  }
}

__global__ __launch_bounds__(256) void hie_final_kernel(
    const float* __restrict__ h, const float* __restrict__ pat,
    const float* __restrict__ Qg, float* __restrict__ outp)
{
  __shared__ float Qs[16][260];
  __shared__ float pt[16][16];
  const int b = blockIdx.x, t = threadIdx.x;
  for (int i = t; i < 4096; i += 256) Qs[i >> 8][i & 255] = Qg[(size_t)b * 4096 + i];
  const int nl = t >> 4, r = t & 15;
  for (int chunk = 0; chunk < 200; chunk += 16) {
    __syncthreads();
    {
      int n = chunk + nl;
      pt[nl][r] = (n < 200) ? pat[((size_t)b * 200 + n) * 16 + r] : 0.0f;
    }
    __syncthreads();
#pragma unroll 1
    for (int j = 0; j < 16; ++j) {
      int n = chunk + j;
      if (n >= 200) break;
      float acc = h[((size_t)b * 200 + n) * 256 + t];
#pragma unroll
      for (int rr = 0; rr < 16; ++rr) acc = fmaf(pt[j][rr], Qs[rr][t], acc);
      outp[((size_t)b * 200 + n) * 256 + t] = acc;
    }
  }
}

// ws-too-small diagnostic: absmax will read ~ws_size in MB at out[0].
__global__ void diag_kernel(float* out, float val, int n) {
  int i = blockIdx.x * 256 + threadIdx.x;
  if (i < n) out[i] = (i == 0) ? val : 0.0f;
}

// ---------------------------------------------------------------------------
extern "C" void kernel_launch(void* const* d_in, const int* in_sizes, int n_in,
                              void* d_out, int out_size, void* d_ws, size_t ws_size,
                              hipStream_t stream)
{
  (void)in_sizes; (void)n_in;
  const float* input  = (const float*)d_in[0];
  const float* fusion = (const float*)d_in[1];
  const float* pos    = (const float*)d_in[2];
  const float* mask   = (const float*)d_in[3];
  const float* Wv  = (const float*)d_in[4];  const float* bv  = (const float*)d_in[5];
  const float* Wqf = (const float*)d_in[6];  const float* bqf = (const float*)d_in[7];
  const float* Wkf = (const float*)d_in[8];  const float* bkf = (const float*)d_in[9];
  const float* Wvf = (const float*)d_in[10]; const float* bvf = (const float*)d_in[11];
  const float* Wqp = (const float*)d_in[12]; const float* bqp = (const float*)d_in[13];
  const float* Wkp = (const float*)d_in[14]; const float* bkp = (const float*)d_in[15];
  const float* Wvp = (const float*)d_in[16]; const float* bvp = (const float*)d_in[17];
  const float* Wd  = (const float*)d_in[18]; const float* bd  = (const float*)d_in[19];
  const float* g1  = (const float*)d_in[20]; const float* b1  = (const float*)d_in[21];
  const float* Wfd = (const float*)d_in[22]; const float* bfd = (const float*)d_in[23];
  const float* g2  = (const float*)d_in[24]; const float* b2  = (const float*)d_in[25];
  const float* Wpd = (const float*)d_in[26]; const float* bpd = (const float*)d_in[27];
  const float* g3  = (const float*)d_in[28]; const float* b3  = (const float*)d_in[29];
  const float* Wr  = (const float*)d_in[30];

  const size_t required = 2 * BSD * 4;   // 104,857,600 bytes
  if (ws_size < required) {
    diag_kernel<<<(out_size + 255) / 256, 256, 0, stream>>>(
        (float*)d_out, (float)(ws_size >> 20), out_size);
    return;
  }

  float* W0 = (float*)d_ws;
  float* W1 = W0 + BSD;
  float* O0 = (float*)d_out;          // hbuf quarters -> out_h (final, in place)
  float* O1 = O0 + BSD;               // out_hf (final)
  float* O2 = O0 + 2 * BSD;           // out_hp (final)
  // quarter slots for projections
  float* s_fq = W0;
  float* s_fk = W0 + QUART;
  float* s_pq = W0 + 2 * QUART;
  float* s_pk = W0 + 3 * QUART;
  float* s_iv = W1;
  float* s_fv = W1 + QUART;
  float* s_pv = W1 + 2 * QUART;
  // HIE smalls in W0 (free after all attention chunks)
  float* hrb  = W0;                   // 1,048,576
  float* Qb   = W0 + 1048576;         // 1,048,576
  float* pxb  = W0 + 2097152;         // 819,200
  float* patb = W0 + 2916352;         // 819,200

  dim3 Blk(256);
  dim3 GG(MQ / 128, 2);               // 100 x 2 GEMM blocks per quarter
  dim3 AG(4, H_, 64);                 // qtile, head, batch
  dim3 LG(MQ / 64);                   // 200 dense_ln blocks per quarter

  for (int c = 0; c < 4; ++c) {
    const size_t o  = (size_t)c * QUART;
    const size_t om = (size_t)c * 64 * 200;
    gemm_proj<<<GG, Blk, 0, stream>>>(fusion + o, Wqf, bqf, s_fq);
    gemm_proj<<<GG, Blk, 0, stream>>>(fusion + o, Wkf, bkf, s_fk);
    gemm_proj<<<GG, Blk, 0, stream>>>(pos + o,    Wqp, bqp, s_pq);
    gemm_proj<<<GG, Blk, 0, stream>>>(pos + o,    Wkp, bkp, s_pk);
    gemm_proj<<<GG, Blk, 0, stream>>>(input + o,  Wv,  bv,  s_iv);
    gemm_proj<<<GG, Blk, 0, stream>>>(fusion + o, Wvf, bvf, s_fv);
    gemm_proj<<<GG, Blk, 0, stream>>>(pos + o,    Wvp, bvp, s_pv);
    fused_attn<<<AG, Blk, 0, stream>>>(s_fq, s_fk, s_pq, s_pk, s_iv, s_fv, s_pv,
                                       mask + om, O0 + o, O1 + o, O2 + o);
    dense_ln_kernel<<<LG, Blk, 0, stream>>>(O0 + o, Wd,  bd,  input + o,  g1, b1, O0 + o);
    dense_ln_kernel<<<LG, Blk, 0, stream>>>(O1 + o, Wfd, bfd, fusion + o, g2, b2, O1 + o);
    dense_ln_kernel<<<LG, Blk, 0, stream>>>(O2 + o, Wpd, bpd, pos + o,    g3, b3, O2 + o);
  }
  // HIE: hbuf = O0, hf = O1; smalls in W0
  hie_hr_kernel<<<B_, Blk, 0, stream>>>(O0, Wr, hrb);
  hie_qr_kernel<<<B_, Blk, 0, stream>>>(hrb, Qb);
  hie_px_kernel<false><<<B_, Blk, 0, stream>>>(O0, Qb, nullptr, pxb);
  hie_px_kernel<true><<<B_, Blk, 0, stream>>>(O1, Qb, pxb, patb);
  hie_final_kernel<<<B_, Blk, 0, stream>>>(O0, patb, Qb, O0);
}